// Round 1
// 457.876 us; speedup vs baseline: 1.0912x; 1.0912x over previous
//
#include <hip/hip_runtime.h>

typedef unsigned short ushort_t;
typedef __attribute__((ext_vector_type(2))) float f32x2;
typedef __attribute__((ext_vector_type(8))) short bfrag;
typedef __attribute__((ext_vector_type(4))) float f32x4;

__device__ __forceinline__ float sigf(float x) { return 1.0f / (1.0f + __expf(-x)); }
__device__ __forceinline__ float tanhf_fast(float x) { return 1.0f - 2.0f / (__expf(2.0f * x) + 1.0f); }
__device__ __forceinline__ ushort_t f2bf(float f) {
    unsigned u = __float_as_uint(f);
    unsigned r = (u + 0x7fffu + ((u >> 16) & 1u)) >> 16;
    return (ushort_t)r;
}

// ---------------------------------------------------------------------------
// K0: batched prep — all 5 weight transposes + sm_w fp32->bf16 cast in ONE
// launch (replaces 6 kernels). Blocks [0,192): 32x32 transpose tiles;
// blocks [192,4192): cast, 1024 elems each.
// ---------------------------------------------------------------------------
__global__ void prep_kernel(const float* __restrict__ eW, float* __restrict__ eWT,
                            const float* __restrict__ dW, float* __restrict__ dWT,
                            const float* __restrict__ w1s, float* __restrict__ w1sT,
                            const float* __restrict__ w1t, float* __restrict__ w1tT,
                            const float* __restrict__ ow, float* __restrict__ owT,
                            const float* __restrict__ smw, ushort_t* __restrict__ smwbf)
{
    int bid = blockIdx.x;
    int tid = threadIdx.x;
    if (bid >= 192) {
        int i = ((bid - 192) * 256 + tid) * 4;   // exact: 4000*1024 = 32000*128
        float4 v = *(const float4*)(smw + i);
        smwbf[i + 0] = f2bf(v.x);
        smwbf[i + 1] = f2bf(v.y);
        smwbf[i + 2] = f2bf(v.z);
        smwbf[i + 3] = f2bf(v.w);
        return;
    }
    __shared__ float tile[32][33];
    const float* in; float* outp; int C; int t;
    if (bid < 64)       { in = eW;  outp = eWT;  C = 128; t = bid; }
    else if (bid < 128) { in = dW;  outp = dWT;  C = 128; t = bid - 64; }
    else if (bid < 144) { in = w1s; outp = w1sT; C = 128; t = bid - 128; }
    else if (bid < 160) { in = w1t; outp = w1tT; C = 128; t = bid - 144; }
    else                { in = ow;  outp = owT;  C = 256; t = bid - 160; }
    int R = (bid < 128) ? 512 : 128;             // all dims exact multiples of 32
    int gx = C >> 5;
    int c0 = (t & (gx - 1)) * 32, r0 = (t / gx) * 32;
    int x = tid & 31, y = tid >> 5;
#pragma unroll
    for (int i = 0; i < 32; i += 8)
        tile[y + i][x] = in[(r0 + y + i) * C + c0 + x];
    __syncthreads();
#pragma unroll
    for (int i = 0; i < 32; i += 8)
        outp[(c0 + y + i) * R + r0 + x] = tile[x][y + i];
}

// ---------------------------------------------------------------------------
// K1 body: out[n][j] = b1[j] (+ b2[j]) + sum_k X[row(n)][k] * WT[k*J + j]
// ---------------------------------------------------------------------------
__device__ __forceinline__ void tok_gemv_body(const float* __restrict__ X,
                                              const int* __restrict__ toks,
                                              int divv,
                                              const float* __restrict__ WT,
                                              const float* __restrict__ b1,
                                              const float* __restrict__ b2,
                                              float* __restrict__ out,
                                              int ntok, int n0, int J, float* xs)
{
    for (int i = threadIdx.x; i < 4 * 128; i += J) {
        int tt = i >> 7, k = i & 127;
        int n = n0 + tt;
        if (n >= ntok) n = ntok - 1;
        int row;
        if (!toks) row = n;
        else if (divv == 0) row = toks[n];
        else { int bb = n / divv; int t = n - bb * divv; row = toks[bb * (divv + 1) + t]; }
        xs[i] = X[row * 128 + k];
    }
    __syncthreads();
    int j = threadIdx.x;
    float bias = b1[j] + (b2 ? b2[j] : 0.0f);
    const float4* x0 = (const float4*)(xs);
    const float4* x1 = (const float4*)(xs + 128);
    const float4* x2 = (const float4*)(xs + 256);
    const float4* x3 = (const float4*)(xs + 384);
    float a0 = 0.f, a1 = 0.f, a2 = 0.f, a3 = 0.f;
#pragma unroll 8
    for (int k4 = 0; k4 < 32; ++k4) {
        float4 v0 = x0[k4], v1 = x1[k4], v2 = x2[k4], v3 = x3[k4];
        float w0 = WT[(k4 * 4 + 0) * J + j];
        float w1 = WT[(k4 * 4 + 1) * J + j];
        float w2_ = WT[(k4 * 4 + 2) * J + j];
        float w3 = WT[(k4 * 4 + 3) * J + j];
        a0 += v0.x * w0 + v0.y * w1 + v0.z * w2_ + v0.w * w3;
        a1 += v1.x * w0 + v1.y * w1 + v1.z * w2_ + v1.w * w3;
        a2 += v2.x * w0 + v2.y * w1 + v2.z * w2_ + v2.w * w3;
        a3 += v3.x * w0 + v3.y * w1 + v3.z * w2_ + v3.w * w3;
    }
    float accs[4] = {a0, a1, a2, a3};
#pragma unroll
    for (int tt = 0; tt < 4; ++tt) {
        int n = n0 + tt;
        if (n < ntok) out[n * J + j] = bias + accs[tt];
    }
}

// att_src path (J = 128)
__global__ void tok_gemv_kernel(const float* __restrict__ X,
                                const int* __restrict__ toks, int divv,
                                const float* __restrict__ WT,
                                const float* __restrict__ b1,
                                const float* __restrict__ b2,
                                float* __restrict__ out, int ntok)
{
    __shared__ __align__(16) float xs[4 * 128];
    tok_gemv_body(X, toks, divv, WT, b1, b2, out, ntok, blockIdx.x * 4, blockDim.x, xs);
}

// enc + dec input-gate precompute in ONE launch (blocks [0,400) enc, [400,792) dec)
__global__ void tok_gemv2_kernel(const float* __restrict__ embS, const int* __restrict__ src,
                                 const float* __restrict__ WTe,
                                 const float* __restrict__ bihE, const float* __restrict__ bhhE,
                                 float* __restrict__ gihE,
                                 const float* __restrict__ embT, const int* __restrict__ trg,
                                 const float* __restrict__ WTd,
                                 const float* __restrict__ bihD, const float* __restrict__ bhhD,
                                 float* __restrict__ gihD)
{
    __shared__ __align__(16) float xs[4 * 128];
    if (blockIdx.x < 400)
        tok_gemv_body(embS, src, 0, WTe, bihE, bhhE, gihE, 1600, blockIdx.x * 4, blockDim.x, xs);
    else
        tok_gemv_body(embT, trg, 49, WTd, bihD, bhhD, gihD, 1568, (blockIdx.x - 400) * 4, blockDim.x, xs);
}

// ---------------------------------------------------------------------------
// K2: combined LSTM recurrences. Blocks 0..31: encoder (T=50), 32..63: decoder
// (T=49). Whh row tid cached in 128 VGPRs; inner matvec as f32x2 packed math
// (v_pk_fma_f32) -> half the VALU issue per step.
// ---------------------------------------------------------------------------
__global__ void __launch_bounds__(512, 2) rnn_kernel(const float* __restrict__ gih_enc,
                                                     const float* __restrict__ enc_Whh,
                                                     const float* __restrict__ gih_dec,
                                                     const float* __restrict__ dec_Whh,
                                                     float* __restrict__ enc_out,
                                                     float* __restrict__ hdec)
{
    bool is_enc = blockIdx.x < 32;
    int b = is_enc ? blockIdx.x : blockIdx.x - 32;
    int T = is_enc ? 50 : 49;
    const float* gih = is_enc ? gih_enc : gih_dec;
    const float* Whh = is_enc ? enc_Whh : dec_Whh;
    float* hout = is_enc ? enc_out : hdec;

    int tid = threadIdx.x;
    __shared__ __align__(16) float h[128];
    __shared__ float gates[512];

    // cache Whh row `tid` in registers as 64 x f32x2 (128 VGPRs)
    f32x2 w2[64];
    const f32x2* wr = (const f32x2*)(Whh + tid * 128);
#pragma unroll
    for (int k = 0; k < 64; ++k) w2[k] = wr[k];

    float c = 0.f;
    if (tid < 128) h[tid] = 0.f;
    const float* gb = gih + b * T * 512 + tid;
    float gnext = gb[0];
    const f32x2* h2 = (const f32x2*)h;

    for (int t = 0; t < T; ++t) {
        __syncthreads();
        float g0 = gnext;
        if (t + 1 < T) gnext = gb[(t + 1) * 512];  // prefetch (independent of h)
        f32x2 s0 = {0.f, 0.f}, s1 = {0.f, 0.f};
#pragma unroll
        for (int k = 0; k < 64; k += 2) {
            s0 += h2[k] * w2[k];        // v_pk_fma_f32
            s1 += h2[k + 1] * w2[k + 1];
        }
        gates[tid] = g0 + s0.x + s0.y + s1.x + s1.y;
        __syncthreads();
        if (tid < 128) {
            float gi = gates[tid], gf = gates[128 + tid], gg = gates[256 + tid], go = gates[384 + tid];
            c = sigf(gf) * c + sigf(gi) * tanhf_fast(gg);
            float hn = sigf(go) * tanhf_fast(c);
            h[tid] = hn;
            hout[(b * T + t) * 128 + tid] = hn;
        }
    }
}

// ---------------------------------------------------------------------------
// K4: fully parallel attention + output projection. One block per (b,t).
// ---------------------------------------------------------------------------
__global__ void __launch_bounds__(128) att_par_kernel(const float* __restrict__ hdec,
                                                      const float* __restrict__ att_src,
                                                      const float* __restrict__ enc_out,
                                                      const float* __restrict__ w1tT,   // 128x128
                                                      const float* __restrict__ b1t,
                                                      const float* __restrict__ w2,
                                                      const float* __restrict__ b2,
                                                      const float* __restrict__ out_wT, // 256x128
                                                      const float* __restrict__ out_b,
                                                      ushort_t* __restrict__ fin_bf)
{
    int t = blockIdx.x, b = blockIdx.y;
    int tid = threadIdx.x, lane = tid & 63, wv = tid >> 6;
    __shared__ __align__(16) float h[128];
    __shared__ __align__(16) float attv[128];
    __shared__ float attt[128];
    __shared__ float sc[64];

    h[tid] = hdec[(b * 49 + t) * 128 + tid];
    __syncthreads();
    const float4* h4 = (const float4*)h;

    // att_tgt = h @ w1t^T + b1t
    {
        float acc = b1t[tid];
#pragma unroll
        for (int k4 = 0; k4 < 32; ++k4) {
            float4 hv = h4[k4];
            int k = k4 * 4;
            acc += hv.x * w1tT[(k + 0) * 128 + tid] + hv.y * w1tT[(k + 1) * 128 + tid]
                 + hv.z * w1tT[(k + 2) * 128 + tid] + hv.w * w1tT[(k + 3) * 128 + tid];
        }
        attt[tid] = acc;
    }
    __syncthreads();
    // scores
    {
        float w2a = w2[lane], w2b = w2[lane + 64], b2s = b2[0];
        float ta = attt[lane], tb = attt[lane + 64];
        const float* asb = att_src + b * 6400;
        for (int s = wv; s < 50; s += 2) {
            float v = w2a * tanhf_fast(asb[s * 128 + lane] + ta)
                    + w2b * tanhf_fast(asb[s * 128 + 64 + lane] + tb);
#pragma unroll
            for (int off = 32; off; off >>= 1) v += __shfl_down(v, off);
            if (lane == 0) sc[s] = v + b2s;
        }
    }
    __syncthreads();
    // softmax over 50 (wave 0)
    if (tid < 64) {
        float x = (tid < 50) ? sc[tid] : -1e30f;
        float m = x;
#pragma unroll
        for (int off = 32; off; off >>= 1) m = fmaxf(m, __shfl_xor(m, off));
        float e = (tid < 50) ? __expf(x - m) : 0.f;
        float ssum = e;
#pragma unroll
        for (int off = 32; off; off >>= 1) ssum += __shfl_xor(ssum, off);
        if (tid < 50) sc[tid] = e / ssum;
    }
    __syncthreads();
    // att_vec
    {
        const float* eob = enc_out + b * 6400;
        float av = 0.f;
        for (int s = 0; s < 50; ++s) av += sc[s] * eob[s * 128 + tid];
        attv[tid] = av;
    }
    __syncthreads();
    // final = tanh([h | attv] @ out_w^T + out_b) -> bf16
    {
        const float4* av4 = (const float4*)attv;
        float a3 = out_b[tid];
#pragma unroll
        for (int k4 = 0; k4 < 32; ++k4) {
            float4 hv = h4[k4];
            int k = k4 * 4;
            a3 += hv.x * out_wT[(k + 0) * 128 + tid] + hv.y * out_wT[(k + 1) * 128 + tid]
                + hv.z * out_wT[(k + 2) * 128 + tid] + hv.w * out_wT[(k + 3) * 128 + tid];
        }
#pragma unroll
        for (int k4 = 0; k4 < 32; ++k4) {
            float4 vv = av4[k4];
            int k = 128 + k4 * 4;
            a3 += vv.x * out_wT[(k + 0) * 128 + tid] + vv.y * out_wT[(k + 1) * 128 + tid]
                + vv.z * out_wT[(k + 2) * 128 + tid] + vv.w * out_wT[(k + 3) * 128 + tid];
        }
        fin_bf[(b * 49 + t) * 128 + tid] = f2bf(tanhf_fast(a3));
    }
}

// ---------------------------------------------------------------------------
// K6: logits = final(1568x128) @ sm_w^T(128x32000) + sm_b, bf16 MFMA.
// Block = 256 thr computes 64 rows x 128 cols. Each wave owns a DISTINCT
// 32-col panel (B loaded once per block, 4x less L1 traffic) and all 4
// row-tiles. Swapped-operand MFMA: mfma(b, a, acc) gives lane&15 = M-row,
// (lane>>4)*4+i = N-col -> one dwordx4 store per 16x16 tile (4x fewer
// store instrs), still full 64B-aligned segments.
// ---------------------------------------------------------------------------
__global__ void __launch_bounds__(256) logits_gemm_kernel(const ushort_t* __restrict__ A,
                                                          const ushort_t* __restrict__ Bw,
                                                          const float* __restrict__ bias,
                                                          float* __restrict__ out)
{
    int wv = threadIdx.x >> 6, lane = threadIdx.x & 63;
    int r = lane & 15, kq = (lane >> 4) * 8;
    int mbase = blockIdx.y * 64;
    int nb = blockIdx.x * 128 + wv * 32;

    bfrag a[4][4];
#pragma unroll
    for (int mt = 0; mt < 4; ++mt) {
        const ushort_t* ap = A + (mbase + mt * 16 + r) * 128 + kq;
#pragma unroll
        for (int kk = 0; kk < 4; ++kk) a[mt][kk] = *(const bfrag*)(ap + kk * 32);
    }
    bfrag bf[2][4];
#pragma unroll
    for (int vt = 0; vt < 2; ++vt) {
        const ushort_t* bp = Bw + (nb + vt * 16 + r) * 128 + kq;
#pragma unroll
        for (int kk = 0; kk < 4; ++kk) bf[vt][kk] = *(const bfrag*)(bp + kk * 32);
    }

#pragma unroll
    for (int mt = 0; mt < 4; ++mt) {
        bool valid = (mbase + mt * 16) < 1568;  // M = 1568 = 98*16, wave-uniform
#pragma unroll
        for (int vt = 0; vt < 2; ++vt) {
            f32x4 acc = {0.f, 0.f, 0.f, 0.f};
            acc = __builtin_amdgcn_mfma_f32_16x16x32_bf16(bf[vt][0], a[mt][0], acc, 0, 0, 0);
            acc = __builtin_amdgcn_mfma_f32_16x16x32_bf16(bf[vt][1], a[mt][1], acc, 0, 0, 0);
            acc = __builtin_amdgcn_mfma_f32_16x16x32_bf16(bf[vt][2], a[mt][2], acc, 0, 0, 0);
            acc = __builtin_amdgcn_mfma_f32_16x16x32_bf16(bf[vt][3], a[mt][3], acc, 0, 0, 0);
            if (valid) {
                int m = mbase + mt * 16 + r;
                int col = nb + vt * 16 + (lane >> 4) * 4;
                float4 bs = *(const float4*)(bias + col);
                float4 st = {acc[0] + bs.x, acc[1] + bs.y, acc[2] + bs.z, acc[3] + bs.w};
                *(float4*)(out + (size_t)m * 32000 + col) = st;
            }
        }
    }
}

extern "C" void kernel_launch(void* const* d_in, const int* in_sizes, int n_in,
                              void* d_out, int out_size, void* d_ws, size_t ws_size,
                              hipStream_t stream)
{
    const int* src      = (const int*)d_in[0];
    const int* trg      = (const int*)d_in[1];
    const float* emb_src = (const float*)d_in[2];
    const float* emb_trg = (const float*)d_in[3];
    const float* enc_Wih = (const float*)d_in[4];
    const float* enc_Whh = (const float*)d_in[5];
    const float* enc_bih = (const float*)d_in[6];
    const float* enc_bhh = (const float*)d_in[7];
    const float* dec_Wih = (const float*)d_in[8];
    const float* dec_Whh = (const float*)d_in[9];
    const float* dec_bih = (const float*)d_in[10];
    const float* dec_bhh = (const float*)d_in[11];
    const float* att_w1s = (const float*)d_in[12];
    const float* att_b1s = (const float*)d_in[13];
    const float* att_w1t = (const float*)d_in[14];
    const float* att_b1t = (const float*)d_in[15];
    const float* att_w2  = (const float*)d_in[16];
    const float* att_b2  = (const float*)d_in[17];
    const float* out_w   = (const float*)d_in[18];
    const float* out_b   = (const float*)d_in[19];
    const float* sm_w    = (const float*)d_in[20];
    const float* sm_b    = (const float*)d_in[21];
    float* out = (float*)d_out;

    // Workspace layout (17.1 MB; att_src overlaps dead gih_enc, fin_bf overlaps
    // dead gih_dec — gih_* are only live until rnn_kernel completes).
    char* ws = (char*)d_ws;
    float*    gih_enc = (float*)(ws);                      // 3,276,800 (phase 1-2)
    float*    att_src = (float*)(ws);                      //   819,200 (phase 3+, overlaps)
    float*    gih_dec = (float*)(ws + 3276800);            // 3,211,264 (phase 1-2)
    ushort_t* fin_bf  = (ushort_t*)(ws + 3276800);         //   401,408 (phase 4+, overlaps)
    float*    enc_out = (float*)(ws + 6488064);            //   819,200
    float*    hdec    = (float*)(ws + 7307264);            //   802,816
    ushort_t* smw_bf  = (ushort_t*)(ws + 8110080);         // 8,192,000
    float*    WihT_e  = (float*)(ws + 16302080);           //   262,144
    float*    WihT_d  = (float*)(ws + 16564224);           //   262,144
    float*    w1sT    = (float*)(ws + 16826368);           //    65,536
    float*    w1tT    = (float*)(ws + 16891904);           //    65,536
    float*    outwT   = (float*)(ws + 16957440);           //   131,072 -> 17,088,512 total

    // K0: all transposes + sm_w cast, one launch
    prep_kernel<<<4192, 256, 0, stream>>>(enc_Wih, WihT_e, dec_Wih, WihT_d,
                                          att_w1s, w1sT, att_w1t, w1tT,
                                          out_w, outwT, sm_w, smw_bf);

    // K1: enc + dec input-gate precompute, one launch
    tok_gemv2_kernel<<<792, 512, 0, stream>>>(emb_src, src, WihT_e, enc_bih, enc_bhh, gih_enc,
                                              emb_trg, trg, WihT_d, dec_bih, dec_bhh, gih_dec);

    // K2: both recurrences concurrently (enc blocks 0..31, dec blocks 32..63)
    rnn_kernel<<<64, 512, 0, stream>>>(gih_enc, enc_Whh, gih_dec, dec_Whh, enc_out, hdec);

    // K3: att_src = enc_out @ w1s^T + b1s
    tok_gemv_kernel<<<400, 128, 0, stream>>>(enc_out, nullptr, 0, w1sT, att_b1s, nullptr, att_src, 1600);

    // K4: fully parallel attention + output projection
    att_par_kernel<<<dim3(49, 32), 128, 0, stream>>>(hdec, att_src, enc_out,
                                                     w1tT, att_b1t, att_w2, att_b2,
                                                     outwT, out_b, fin_bf);

    // K6: big output GEMM (bf16 MFMA, fp32 accumulate)
    logits_gemm_kernel<<<dim3(250, 25), 256, 0, stream>>>(fin_bf, smw_bf, sm_b, out);
}

// Round 2
// 438.714 us; speedup vs baseline: 1.1389x; 1.0437x over previous
//
#include <hip/hip_runtime.h>

typedef unsigned short ushort_t;
typedef __attribute__((ext_vector_type(2))) float f32x2;
typedef __attribute__((ext_vector_type(8))) short bfrag;
typedef __attribute__((ext_vector_type(4))) float f32x4;

__device__ __forceinline__ float sigf(float x) { return 1.0f / (1.0f + __expf(-x)); }
__device__ __forceinline__ float tanhf_fast(float x) { return 1.0f - 2.0f / (__expf(2.0f * x) + 1.0f); }
__device__ __forceinline__ ushort_t f2bf(float f) {
    unsigned u = __float_as_uint(f);
    unsigned r = (u + 0x7fffu + ((u >> 16) & 1u)) >> 16;
    return (ushort_t)r;
}

// ---------------------------------------------------------------------------
// K0: batched prep — all 5 weight transposes in ONE launch. (sm_w cast is now
// fused into logits_gemm's one-time B-register load.)
// ---------------------------------------------------------------------------
__global__ void prep_kernel(const float* __restrict__ eW, float* __restrict__ eWT,
                            const float* __restrict__ dW, float* __restrict__ dWT,
                            const float* __restrict__ w1s, float* __restrict__ w1sT,
                            const float* __restrict__ w1t, float* __restrict__ w1tT,
                            const float* __restrict__ ow, float* __restrict__ owT)
{
    int bid = blockIdx.x;
    int tid = threadIdx.x;
    __shared__ float tile[32][33];
    const float* in; float* outp; int C; int t;
    if (bid < 64)       { in = eW;  outp = eWT;  C = 128; t = bid; }
    else if (bid < 128) { in = dW;  outp = dWT;  C = 128; t = bid - 64; }
    else if (bid < 144) { in = w1s; outp = w1sT; C = 128; t = bid - 128; }
    else if (bid < 160) { in = w1t; outp = w1tT; C = 128; t = bid - 144; }
    else                { in = ow;  outp = owT;  C = 256; t = bid - 160; }
    int R = (bid < 128) ? 512 : 128;             // all dims exact multiples of 32
    int gx = C >> 5;
    int c0 = (t & (gx - 1)) * 32, r0 = (t / gx) * 32;
    int x = tid & 31, y = tid >> 5;
#pragma unroll
    for (int i = 0; i < 32; i += 8)
        tile[y + i][x] = in[(r0 + y + i) * C + c0 + x];
    __syncthreads();
#pragma unroll
    for (int i = 0; i < 32; i += 8)
        outp[(c0 + y + i) * R + r0 + x] = tile[x][y + i];
}

// ---------------------------------------------------------------------------
// K1 body: out[n][j] = b1[j] (+ b2[j]) + sum_k X[row(n)][k] * WT[k*J + j]
// ---------------------------------------------------------------------------
__device__ __forceinline__ void tok_gemv_body(const float* __restrict__ X,
                                              const int* __restrict__ toks,
                                              int divv,
                                              const float* __restrict__ WT,
                                              const float* __restrict__ b1,
                                              const float* __restrict__ b2,
                                              float* __restrict__ out,
                                              int ntok, int n0, int J, float* xs)
{
    for (int i = threadIdx.x; i < 4 * 128; i += J) {
        int tt = i >> 7, k = i & 127;
        int n = n0 + tt;
        if (n >= ntok) n = ntok - 1;
        int row;
        if (!toks) row = n;
        else if (divv == 0) row = toks[n];
        else { int bb = n / divv; int t = n - bb * divv; row = toks[bb * (divv + 1) + t]; }
        xs[i] = X[row * 128 + k];
    }
    __syncthreads();
    int j = threadIdx.x;
    float bias = b1[j] + (b2 ? b2[j] : 0.0f);
    const float4* x0 = (const float4*)(xs);
    const float4* x1 = (const float4*)(xs + 128);
    const float4* x2 = (const float4*)(xs + 256);
    const float4* x3 = (const float4*)(xs + 384);
    float a0 = 0.f, a1 = 0.f, a2 = 0.f, a3 = 0.f;
#pragma unroll 8
    for (int k4 = 0; k4 < 32; ++k4) {
        float4 v0 = x0[k4], v1 = x1[k4], v2 = x2[k4], v3 = x3[k4];
        float w0 = WT[(k4 * 4 + 0) * J + j];
        float w1 = WT[(k4 * 4 + 1) * J + j];
        float w2_ = WT[(k4 * 4 + 2) * J + j];
        float w3 = WT[(k4 * 4 + 3) * J + j];
        a0 += v0.x * w0 + v0.y * w1 + v0.z * w2_ + v0.w * w3;
        a1 += v1.x * w0 + v1.y * w1 + v1.z * w2_ + v1.w * w3;
        a2 += v2.x * w0 + v2.y * w1 + v2.z * w2_ + v2.w * w3;
        a3 += v3.x * w0 + v3.y * w1 + v3.z * w2_ + v3.w * w3;
    }
    float accs[4] = {a0, a1, a2, a3};
#pragma unroll
    for (int tt = 0; tt < 4; ++tt) {
        int n = n0 + tt;
        if (n < ntok) out[n * J + j] = bias + accs[tt];
    }
}

// att_src path (J = 128)
__global__ void tok_gemv_kernel(const float* __restrict__ X,
                                const int* __restrict__ toks, int divv,
                                const float* __restrict__ WT,
                                const float* __restrict__ b1,
                                const float* __restrict__ b2,
                                float* __restrict__ out, int ntok)
{
    __shared__ __align__(16) float xs[4 * 128];
    tok_gemv_body(X, toks, divv, WT, b1, b2, out, ntok, blockIdx.x * 4, blockDim.x, xs);
}

// enc + dec input-gate precompute in ONE launch (blocks [0,400) enc, [400,792) dec)
__global__ void tok_gemv2_kernel(const float* __restrict__ embS, const int* __restrict__ src,
                                 const float* __restrict__ WTe,
                                 const float* __restrict__ bihE, const float* __restrict__ bhhE,
                                 float* __restrict__ gihE,
                                 const float* __restrict__ embT, const int* __restrict__ trg,
                                 const float* __restrict__ WTd,
                                 const float* __restrict__ bihD, const float* __restrict__ bhhD,
                                 float* __restrict__ gihD)
{
    __shared__ __align__(16) float xs[4 * 128];
    if (blockIdx.x < 400)
        tok_gemv_body(embS, src, 0, WTe, bihE, bhhE, gihE, 1600, blockIdx.x * 4, blockDim.x, xs);
    else
        tok_gemv_body(embT, trg, 49, WTd, bihD, bhhD, gihD, 1568, (blockIdx.x - 400) * 4, blockDim.x, xs);
}

// ---------------------------------------------------------------------------
// K2: combined LSTM recurrences. Blocks 0..31: encoder (T=50), 32..63: decoder
// (T=49). Whh row tid cached in 128 VGPRs; h read via ds_read_b128 broadcast;
// gate nonlinearities applied in the 512-wide stage (parallel) instead of the
// 128-thread tail.
// ---------------------------------------------------------------------------
__global__ void __launch_bounds__(512, 2) rnn_kernel(const float* __restrict__ gih_enc,
                                                     const float* __restrict__ enc_Whh,
                                                     const float* __restrict__ gih_dec,
                                                     const float* __restrict__ dec_Whh,
                                                     float* __restrict__ enc_out,
                                                     float* __restrict__ hdec)
{
    bool is_enc = blockIdx.x < 32;
    int b = is_enc ? blockIdx.x : blockIdx.x - 32;
    int T = is_enc ? 50 : 49;
    const float* gih = is_enc ? gih_enc : gih_dec;
    const float* Whh = is_enc ? enc_Whh : dec_Whh;
    float* hout = is_enc ? enc_out : hdec;

    int tid = threadIdx.x;
    __shared__ __align__(16) float h[128];
    __shared__ float gates[512];

    // cache Whh row `tid` in registers (128 VGPRs, float4 granular)
    float4 w4[32];
    const float4* wr = (const float4*)(Whh + tid * 128);
#pragma unroll
    for (int k = 0; k < 32; ++k) w4[k] = wr[k];

    float c = 0.f;
    if (tid < 128) h[tid] = 0.f;
    const float* gb = gih + b * T * 512 + tid;
    float gnext = gb[0];
    const float4* h4 = (const float4*)h;
    int gt = tid >> 7;  // 0:i 1:f 2:g 3:o (wave-uniform)

    for (int t = 0; t < T; ++t) {
        __syncthreads();
        float g0 = gnext;
        if (t + 1 < T) gnext = gb[(t + 1) * 512];  // prefetch (independent of h)
        f32x2 s0 = {0.f, 0.f}, s1 = {0.f, 0.f};
#pragma unroll
        for (int k = 0; k < 32; ++k) {
            float4 hv = h4[k];                    // ds_read_b128 broadcast
            f32x2 ha = {hv.x, hv.y}, hb = {hv.z, hv.w};
            f32x2 wa = {w4[k].x, w4[k].y}, wb = {w4[k].z, w4[k].w};
            s0 += ha * wa;                        // v_pk_fma_f32
            s1 += hb * wb;
        }
        float acc = g0 + s0.x + s0.y + s1.x + s1.y;
        gates[tid] = (gt == 2) ? tanhf_fast(acc) : sigf(acc);  // activation here (512-wide)
        __syncthreads();
        if (tid < 128) {
            float ai = gates[tid], af = gates[128 + tid], ag = gates[256 + tid], ao = gates[384 + tid];
            c = af * c + ai * ag;
            float hn = ao * tanhf_fast(c);
            h[tid] = hn;
            hout[(b * T + t) * 128 + tid] = hn;
        }
    }
}

// ---------------------------------------------------------------------------
// K4: attention + output projection, TWO decoder steps per block (grid 25x32).
// Both t share every weight/att_src/enc_out load -> half the L2 read traffic.
// Softmax for t0/t1 runs on wave0/wave1 concurrently.
// ---------------------------------------------------------------------------
__global__ void __launch_bounds__(128) att_par_kernel(const float* __restrict__ hdec,
                                                      const float* __restrict__ att_src,
                                                      const float* __restrict__ enc_out,
                                                      const float* __restrict__ w1tT,   // 128x128
                                                      const float* __restrict__ b1t,
                                                      const float* __restrict__ w2,
                                                      const float* __restrict__ b2,
                                                      const float* __restrict__ out_wT, // 256x128
                                                      const float* __restrict__ out_b,
                                                      ushort_t* __restrict__ fin_bf)
{
    int b = blockIdx.y;
    int t0 = blockIdx.x * 2;
    int t1 = t0 + 1; if (t1 > 48) t1 = 48;   // edge: duplicate work, same stores
    int tid = threadIdx.x, lane = tid & 63, wv = tid >> 6;
    __shared__ __align__(16) float h0[128], h1[128];
    __shared__ __align__(16) float av0s[128], av1s[128];
    __shared__ float attt0[128], attt1[128];
    __shared__ float sc0[64], sc1[64];

    h0[tid] = hdec[(b * 49 + t0) * 128 + tid];
    h1[tid] = hdec[(b * 49 + t1) * 128 + tid];
    __syncthreads();
    const float4* h04 = (const float4*)h0;
    const float4* h14 = (const float4*)h1;

    // att_tgt for both t, shared weight loads
    {
        float acc0 = b1t[tid], acc1 = acc0;
#pragma unroll
        for (int k4 = 0; k4 < 32; ++k4) {
            float4 hv0 = h04[k4], hv1 = h14[k4];
            int k = k4 * 4;
            float wA = w1tT[(k + 0) * 128 + tid], wB = w1tT[(k + 1) * 128 + tid];
            float wC = w1tT[(k + 2) * 128 + tid], wD = w1tT[(k + 3) * 128 + tid];
            acc0 += hv0.x * wA + hv0.y * wB + hv0.z * wC + hv0.w * wD;
            acc1 += hv1.x * wA + hv1.y * wB + hv1.z * wC + hv1.w * wD;
        }
        attt0[tid] = acc0; attt1[tid] = acc1;
    }
    __syncthreads();
    // scores for both t, shared att_src loads
    {
        float w2a = w2[lane], w2b = w2[lane + 64], b2s = b2[0];
        float ta0 = attt0[lane], tb0 = attt0[lane + 64];
        float ta1 = attt1[lane], tb1 = attt1[lane + 64];
        const float* asb = att_src + b * 6400;
        for (int s = wv; s < 50; s += 2) {
            float lo = asb[s * 128 + lane], hi = asb[s * 128 + 64 + lane];
            float v0 = w2a * tanhf_fast(lo + ta0) + w2b * tanhf_fast(hi + tb0);
            float v1 = w2a * tanhf_fast(lo + ta1) + w2b * tanhf_fast(hi + tb1);
#pragma unroll
            for (int off = 32; off; off >>= 1) {
                v0 += __shfl_down(v0, off);
                v1 += __shfl_down(v1, off);
            }
            if (lane == 0) { sc0[s] = v0 + b2s; sc1[s] = v1 + b2s; }
        }
    }
    __syncthreads();
    // softmax over 50: wave0 -> sc0, wave1 -> sc1
    {
        float* scp = wv ? sc1 : sc0;
        float x = (lane < 50) ? scp[lane] : -1e30f;
        float m = x;
#pragma unroll
        for (int off = 32; off; off >>= 1) m = fmaxf(m, __shfl_xor(m, off));
        float e = (lane < 50) ? __expf(x - m) : 0.f;
        float ssum = e;
#pragma unroll
        for (int off = 32; off; off >>= 1) ssum += __shfl_xor(ssum, off);
        if (lane < 50) scp[lane] = e / ssum;
    }
    __syncthreads();
    // att_vec for both t, shared enc_out loads
    {
        const float* eob = enc_out + b * 6400;
        float a0 = 0.f, a1 = 0.f;
        for (int s = 0; s < 50; ++s) {
            float ev = eob[s * 128 + tid];
            a0 += sc0[s] * ev; a1 += sc1[s] * ev;
        }
        av0s[tid] = a0; av1s[tid] = a1;
    }
    __syncthreads();
    // final = tanh([h | attv] @ out_w^T + out_b) -> bf16, shared weight loads
    {
        const float4* a04 = (const float4*)av0s;
        const float4* a14 = (const float4*)av1s;
        float f0 = out_b[tid], f1 = f0;
#pragma unroll
        for (int k4 = 0; k4 < 32; ++k4) {
            float4 hv0 = h04[k4], hv1 = h14[k4];
            int k = k4 * 4;
            float wA = out_wT[(k + 0) * 128 + tid], wB = out_wT[(k + 1) * 128 + tid];
            float wC = out_wT[(k + 2) * 128 + tid], wD = out_wT[(k + 3) * 128 + tid];
            f0 += hv0.x * wA + hv0.y * wB + hv0.z * wC + hv0.w * wD;
            f1 += hv1.x * wA + hv1.y * wB + hv1.z * wC + hv1.w * wD;
        }
#pragma unroll
        for (int k4 = 0; k4 < 32; ++k4) {
            float4 v0 = a04[k4], v1 = a14[k4];
            int k = 128 + k4 * 4;
            float wA = out_wT[(k + 0) * 128 + tid], wB = out_wT[(k + 1) * 128 + tid];
            float wC = out_wT[(k + 2) * 128 + tid], wD = out_wT[(k + 3) * 128 + tid];
            f0 += v0.x * wA + v0.y * wB + v0.z * wC + v0.w * wD;
            f1 += v1.x * wA + v1.y * wB + v1.z * wC + v1.w * wD;
        }
        fin_bf[(b * 49 + t0) * 128 + tid] = f2bf(tanhf_fast(f0));
        fin_bf[(b * 49 + t1) * 128 + tid] = f2bf(tanhf_fast(f1));
    }
}

// ---------------------------------------------------------------------------
// K6: logits = final(1568x128) @ sm_w^T(128x32000) + sm_b, bf16 MFMA.
// 500 blocks x 256 thr; each block owns a 64-col panel and loops ALL 98
// row-tiles. B panel: loaded ONCE as f32 (the bf16 cast is fused here —
// separate cast kernel eliminated) and held in registers (16 VGPR/wave).
// Swapped-operand MFMA -> one dwordx4 store per tile per wave. A prefetched
// one tile ahead. M=1568=98*16, N=32000=500*64: no bounds checks.
// ---------------------------------------------------------------------------
__global__ void __launch_bounds__(256) logits_gemm_kernel(const ushort_t* __restrict__ A,
                                                          const float* __restrict__ Bw,
                                                          const float* __restrict__ bias,
                                                          float* __restrict__ out)
{
    int wv = threadIdx.x >> 6, lane = threadIdx.x & 63;
    int r = lane & 15, kq = (lane >> 4) * 8;
    int nb = blockIdx.x * 64 + wv * 16;      // this wave's 16-col tile

    // one-time: B tile f32 -> bf16 fragments in registers
    bfrag bf[4];
    {
        const float* bp = Bw + (size_t)(nb + r) * 128 + kq;
#pragma unroll
        for (int kk = 0; kk < 4; ++kk) {
            float4 lo = *(const float4*)(bp + kk * 32);
            float4 hi = *(const float4*)(bp + kk * 32 + 4);
            bfrag f;
            f[0] = (short)f2bf(lo.x); f[1] = (short)f2bf(lo.y);
            f[2] = (short)f2bf(lo.z); f[3] = (short)f2bf(lo.w);
            f[4] = (short)f2bf(hi.x); f[5] = (short)f2bf(hi.y);
            f[6] = (short)f2bf(hi.z); f[7] = (short)f2bf(hi.w);
            bf[kk] = f;
        }
    }
    int colq = (lane >> 4) * 4;
    float4 bs = *(const float4*)(bias + nb + colq);

    const ushort_t* ab = A + r * 128 + kq;
    bfrag a0 = *(const bfrag*)(ab);
    bfrag a1 = *(const bfrag*)(ab + 32);
    bfrag a2 = *(const bfrag*)(ab + 64);
    bfrag a3 = *(const bfrag*)(ab + 96);

    for (int mt = 0; mt < 98; ++mt) {
        bfrag c0 = a0, c1 = a1, c2 = a2, c3 = a3;
        if (mt < 97) {
            const ushort_t* np = ab + (mt + 1) * 16 * 128;
            a0 = *(const bfrag*)(np);
            a1 = *(const bfrag*)(np + 32);
            a2 = *(const bfrag*)(np + 64);
            a3 = *(const bfrag*)(np + 96);
        }
        f32x4 acc = {0.f, 0.f, 0.f, 0.f};
        acc = __builtin_amdgcn_mfma_f32_16x16x32_bf16(bf[0], c0, acc, 0, 0, 0);
        acc = __builtin_amdgcn_mfma_f32_16x16x32_bf16(bf[1], c1, acc, 0, 0, 0);
        acc = __builtin_amdgcn_mfma_f32_16x16x32_bf16(bf[2], c2, acc, 0, 0, 0);
        acc = __builtin_amdgcn_mfma_f32_16x16x32_bf16(bf[3], c3, acc, 0, 0, 0);
        int m = mt * 16 + r;
        float4 st = {acc[0] + bs.x, acc[1] + bs.y, acc[2] + bs.z, acc[3] + bs.w};
        *(float4*)(out + (size_t)m * 32000 + nb + colq) = st;
    }
}

extern "C" void kernel_launch(void* const* d_in, const int* in_sizes, int n_in,
                              void* d_out, int out_size, void* d_ws, size_t ws_size,
                              hipStream_t stream)
{
    const int* src      = (const int*)d_in[0];
    const int* trg      = (const int*)d_in[1];
    const float* emb_src = (const float*)d_in[2];
    const float* emb_trg = (const float*)d_in[3];
    const float* enc_Wih = (const float*)d_in[4];
    const float* enc_Whh = (const float*)d_in[5];
    const float* enc_bih = (const float*)d_in[6];
    const float* enc_bhh = (const float*)d_in[7];
    const float* dec_Wih = (const float*)d_in[8];
    const float* dec_Whh = (const float*)d_in[9];
    const float* dec_bih = (const float*)d_in[10];
    const float* dec_bhh = (const float*)d_in[11];
    const float* att_w1s = (const float*)d_in[12];
    const float* att_b1s = (const float*)d_in[13];
    const float* att_w1t = (const float*)d_in[14];
    const float* att_b1t = (const float*)d_in[15];
    const float* att_w2  = (const float*)d_in[16];
    const float* att_b2  = (const float*)d_in[17];
    const float* out_w   = (const float*)d_in[18];
    const float* out_b   = (const float*)d_in[19];
    const float* sm_w    = (const float*)d_in[20];
    const float* sm_b    = (const float*)d_in[21];
    float* out = (float*)d_out;

    // Workspace layout (att_src overlaps dead gih_enc, fin_bf overlaps dead
    // gih_dec — gih_* are only live until rnn_kernel completes).
    char* ws = (char*)d_ws;
    float*    gih_enc = (float*)(ws);                      // 3,276,800 (phase 1-2)
    float*    att_src = (float*)(ws);                      //   819,200 (phase 3+, overlaps)
    float*    gih_dec = (float*)(ws + 3276800);            // 3,211,264 (phase 1-2)
    ushort_t* fin_bf  = (ushort_t*)(ws + 3276800);         //   401,408 (phase 4+, overlaps)
    float*    enc_out = (float*)(ws + 6488064);            //   819,200
    float*    hdec    = (float*)(ws + 7307264);            //   802,816
    float*    WihT_e  = (float*)(ws + 8110080);            //   262,144
    float*    WihT_d  = (float*)(ws + 8372224);            //   262,144
    float*    w1sT    = (float*)(ws + 8634368);            //    65,536
    float*    w1tT    = (float*)(ws + 8699904);            //    65,536
    float*    outwT   = (float*)(ws + 8765440);            //   131,072 -> 8,896,512 total

    // K0: all transposes, one launch (cast eliminated — fused into K6)
    prep_kernel<<<192, 256, 0, stream>>>(enc_Wih, WihT_e, dec_Wih, WihT_d,
                                         att_w1s, w1sT, att_w1t, w1tT,
                                         out_w, outwT);

    // K1: enc + dec input-gate precompute, one launch
    tok_gemv2_kernel<<<792, 512, 0, stream>>>(emb_src, src, WihT_e, enc_bih, enc_bhh, gih_enc,
                                              emb_trg, trg, WihT_d, dec_bih, dec_bhh, gih_dec);

    // K2: both recurrences concurrently (enc blocks 0..31, dec blocks 32..63)
    rnn_kernel<<<64, 512, 0, stream>>>(gih_enc, enc_Whh, gih_dec, dec_Whh, enc_out, hdec);

    // K3: att_src = enc_out @ w1s^T + b1s
    tok_gemv_kernel<<<400, 128, 0, stream>>>(enc_out, nullptr, 0, w1sT, att_b1s, nullptr, att_src, 1600);

    // K4: attention + output projection, 2 decoder steps per block
    att_par_kernel<<<dim3(25, 32), 128, 0, stream>>>(hdec, att_src, enc_out,
                                                     w1tT, att_b1t, att_w2, att_b2,
                                                     outwT, out_b, fin_bf);

    // K6: big output GEMM (bf16 MFMA, fused sm_w cast, B-resident-in-regs)
    logits_gemm_kernel<<<500, 256, 0, stream>>>(fin_bf, sm_w, sm_b, out);
}